// Round 13
// baseline (128.918 us; speedup 1.0000x reference)
//
#include <hip/hip_runtime.h>

typedef unsigned short u16;
typedef __attribute__((ext_vector_type(8))) short bf16x8;   // 8 bf16 (4 VGPRs)
typedef __attribute__((ext_vector_type(4))) float f32x4;

#define HEADS 12
#define HDIM  64
#define EMBED 768
#define TD    2304
#define SEQ   1024
#define MTOK  8192
#define GK    768
#define GNT   12    // GK / 64
#define LOG2E 1.4426950408889634f

// HW 2^x: compiler-known TRANS intrinsic (hazard-safe), not inline asm.
#if __has_builtin(__builtin_amdgcn_exp2f)
#define EXP2(x) __builtin_amdgcn_exp2f(x)
#else
#define EXP2(x) exp2f(x)
#endif

// round-to-nearest-even f32 -> bf16
__device__ __forceinline__ u16 f2bf(float f) {
  union { float f; unsigned u; } x; x.f = f;
  unsigned r = x.u + 0x7fffu + ((x.u >> 16) & 1u);
  return (u16)(r >> 16);
}

// pack 2 f32 -> 2 bf16 in one inst (D[15:0]=lo, D[31:16]=hi) — T12 recipe
__device__ __forceinline__ unsigned cvt_pk_bf16(float lo, float hi) {
  unsigned r;
  asm("v_cvt_pk_bf16_f32 %0, %1, %2" : "=v"(r) : "v"(lo), "v"(hi));
  return r;
}

// all three f32->bf16 casts in one launch
__global__ void cast3_kernel(const float* __restrict__ x, const float* __restrict__ wq,
                             const float* __restrict__ wp, u16* __restrict__ xb,
                             u16* __restrict__ wqb, u16* __restrict__ wpb) {
  const int N1 = MTOK * EMBED / 4, N2 = TD * EMBED / 4, N3 = EMBED * EMBED / 4;
  int i = blockIdx.x * blockDim.x + threadIdx.x;
  int st = gridDim.x * blockDim.x;
  for (; i < N1 + N2 + N3; i += st) {
    const float* s; u16* d; int j;
    if (i < N1)           { s = x;  d = xb;  j = i; }
    else if (i < N1 + N2) { s = wq; d = wqb; j = i - N1; }
    else                  { s = wp; d = wpb; j = i - N1 - N2; }
    float4 v = reinterpret_cast<const float4*>(s)[j];
    ushort4 o;
    o.x = f2bf(v.x); o.y = f2bf(v.y); o.z = f2bf(v.z); o.w = f2bf(v.w);
    reinterpret_cast<ushort4*>(d)[j] = o;
  }
}

__device__ __forceinline__ void gload_lds16(const u16* g, u16* l) {
  __builtin_amdgcn_global_load_lds(
      (const __attribute__((address_space(1))) unsigned*)g,
      (__attribute__((address_space(3))) unsigned*)l, 16, 0, 0);
}

__device__ __forceinline__ void memfence_bar() {
  asm volatile("" ::: "memory");
  __builtin_amdgcn_s_barrier();
  asm volatile("" ::: "memory");
}

// ---------------- QKV GEMM: 128x128 tile, 64x64 wave tiles, 2-way ny-merge --
// Grid 64x9 = 576 blocks (1.125 rounds @ 2/CU). Block handles ny-tiles
// {ny, ny+9} of 18 in one continuous 24-iter pipeline. A dbuf + B dbuf =
// 64 KB. Single barrier per iter (m97-style); stage t+1 at top, vmcnt(0) at
// end (issued ~1 full iter earlier). Epilogue per tile-region: 0-5 Q (xLOG2E),
// 6-11 K, 12-17 V transposed into vt[bh][e][tok].
__global__ __launch_bounds__(256, 2) void gemm_qkv(const u16* __restrict__ A,
                                                   const u16* __restrict__ B,
                                                   const float* __restrict__ bias,
                                                   u16* __restrict__ Cq,
                                                   u16* __restrict__ vt) {
  __shared__ u16 As[2][128 * 64];   // 2 x 16 KB
  __shared__ u16 Bs[2][128 * 64];   // 2 x 16 KB
  const int tid  = threadIdx.x;
  const int wave = tid >> 6, lane = tid & 63;
  const int wr = wave >> 1, wc = wave & 1;
  const int lr = lane & 15, g = lane >> 4;

  const int swz = (blockIdx.x & 7) * 72 + (blockIdx.x >> 3);   // 576 = 8*72
  const int ny = swz % 9, mx = swz / 9;

  const u16* Ag = A + (size_t)(mx * 128) * GK;

  const int srow   = lane >> 3;             // row within 8-row slot
  const int schunk = (lane & 7) ^ srow;     // pre-swizzled source 16B-chunk

  auto stageA = [&](int u) {                // 4 gloads/thread; kt = u%12
    u16* dst = As[u & 1];
    const int k0 = (u % GNT) * 64;
#pragma unroll
    for (int c = 0; c < 4; ++c) {
      int slot = wave * 4 + c;              // 0..15, 8 rows each
      int row  = slot * 8 + srow;
      gload_lds16(Ag + (size_t)row * GK + k0 + schunk * 8, &dst[slot * 512]);
    }
  };
  auto stageB = [&](int u) {                // 4 gloads/thread
    u16* dst = Bs[u & 1];
    const int k0 = (u % GNT) * 64;
    const u16* Bg = B + (size_t)((ny + (u / GNT) * 9) * 128) * GK;
#pragma unroll
    for (int c = 0; c < 4; ++c) {
      int slot = wave * 4 + c;
      int row  = slot * 8 + srow;
      gload_lds16(Bg + (size_t)row * GK + k0 + schunk * 8, &dst[slot * 512]);
    }
  };

  f32x4 acc[4][4];
#pragma unroll
  for (int m = 0; m < 4; ++m)
#pragma unroll
    for (int n = 0; n < 4; ++n) acc[m][n] = 0.f;

  const int TOT = 2 * GNT;   // 24
  stageA(0);
  stageB(0);
  asm volatile("s_waitcnt vmcnt(0)" ::: "memory");
  memfence_bar();

  for (int u = 0; u < TOT; ++u) {
    if (u + 1 < TOT) { stageA(u + 1); stageB(u + 1); }

    const u16* Ab = As[u & 1];
    const u16* Bb = Bs[u & 1];
    bf16x8 af[4][2], bfr[4][2];
#pragma unroll
    for (int m = 0; m < 4; ++m)
#pragma unroll
      for (int kk = 0; kk < 2; ++kk) {
        int r = wr * 64 + m * 16 + lr;
        af[m][kk] = *reinterpret_cast<const bf16x8*>(
            &Ab[r * 64 + (((kk * 4 + g) ^ (r & 7)) << 3)]);
      }
#pragma unroll
    for (int n = 0; n < 4; ++n)
#pragma unroll
      for (int kk = 0; kk < 2; ++kk) {
        int r = wc * 64 + n * 16 + lr;
        bfr[n][kk] = *reinterpret_cast<const bf16x8*>(
            &Bb[r * 64 + (((kk * 4 + g) ^ (r & 7)) << 3)]);
      }

    __builtin_amdgcn_s_setprio(1);
#pragma unroll
    for (int m = 0; m < 4; ++m)
#pragma unroll
      for (int n = 0; n < 4; ++n) {
        acc[m][n] = __builtin_amdgcn_mfma_f32_16x16x32_bf16(bfr[n][0], af[m][0], acc[m][n], 0, 0, 0);
        acc[m][n] = __builtin_amdgcn_mfma_f32_16x16x32_bf16(bfr[n][1], af[m][1], acc[m][n], 0, 0, 0);
      }
    __builtin_amdgcn_s_setprio(0);

    if (u + 1 < TOT) {
      asm volatile("s_waitcnt vmcnt(0)" ::: "memory");  // t+1 staged (issued ~1 iter ago)
      memfence_bar();
    }

    if ((u % GNT) == GNT - 1) {
      // ---- epilogue for ny-tile nye = ny + (u/12)*9 ----
      const int nye = ny + (u / GNT) * 9;
      const int row0 = mx * 128 + wr * 64 + lr;
      const int col0 = nye * 128 + wc * 64 + g * 4;
      if (nye < 12) {
        const float sc = (nye < 6) ? LOG2E : 1.f;   // Q pre-scaled for exp2
#pragma unroll
        for (int m = 0; m < 4; ++m)
#pragma unroll
          for (int n = 0; n < 4; ++n) {
            int row = row0 + m * 16;
            int col = col0 + n * 16;
            float4 bv = *reinterpret_cast<const float4*>(&bias[col]);
            ushort4 pw;
            pw.x = f2bf((acc[m][n][0] + bv.x) * sc);
            pw.y = f2bf((acc[m][n][1] + bv.y) * sc);
            pw.z = f2bf((acc[m][n][2] + bv.z) * sc);
            pw.w = f2bf((acc[m][n][3] + bv.w) * sc);
            *reinterpret_cast<ushort4*>(&Cq[(size_t)row * TD + col]) = pw;
            acc[m][n] = 0.f;
          }
      } else {
        // V columns: write transposed into vt[bh][e][tok]
#pragma unroll
        for (int m = 0; m < 4; ++m) {
          int row = row0 + m * 16;                 // token
          int b   = row >> 10;
          int tk  = row & 1023;
#pragma unroll
          for (int n = 0; n < 4; ++n) {
            int col = col0 + n * 16;
            float4 bv = *reinterpret_cast<const float4*>(&bias[col]);
#pragma unroll
            for (int j = 0; j < 4; ++j) {
              int vcol = col + j - 2 * EMBED;      // 0..767
              int h = vcol >> 6, e = vcol & 63;
              float v = acc[m][n][j] + (j == 0 ? bv.x : j == 1 ? bv.y : j == 2 ? bv.z : bv.w);
              vt[((size_t)(b * HEADS + h) * HDIM + e) * SEQ + tk] = f2bf(v);
            }
            acc[m][n] = 0.f;
          }
        }
      }
    }
  }
}

// ---------------- proj GEMM (min-2-phase, unchanged) ----------------
template <bool OUT_BF16>
__global__ __launch_bounds__(256, 2) void gemm_min2(const u16* __restrict__ A,
                                                    const u16* __restrict__ B,
                                                    const float* __restrict__ bias,
                                                    void* __restrict__ Cv,
                                                    int NBN, int Ndim) {
  __shared__ u16 As[3][128 * 64];
  __shared__ u16 Bs[2][96 * 64];
  const int tid  = threadIdx.x;
  const int wave = tid >> 6, lane = tid & 63;
  const int wr = wave >> 1, wc = wave & 1;
  const int lr = lane & 15, g = lane >> 4;

  const int nwg = gridDim.x;
  const int swz = (blockIdx.x & 7) * (nwg >> 3) + (blockIdx.x >> 3);
  const int ny = swz % NBN, mx = swz / NBN;

  const u16* Ag = A + (size_t)(mx * 128) * GK;
  const u16* Bg = B + (size_t)(ny * 96) * GK;

  const int srow   = lane >> 3;
  const int schunk = (lane & 7) ^ srow;

  auto stageA = [&](int kt) {
    u16* dst = As[kt % 3];
#pragma unroll
    for (int c = 0; c < 4; ++c) {
      int slot = wave * 4 + c;
      int row  = slot * 8 + srow;
      gload_lds16(Ag + (size_t)row * GK + kt * 64 + schunk * 8, &dst[slot * 512]);
    }
  };
  auto stageB = [&](int kt) {
    u16* dst = Bs[kt & 1];
#pragma unroll
    for (int c = 0; c < 3; ++c) {
      int slot = wave * 3 + c;
      int row  = slot * 8 + srow;
      gload_lds16(Bg + (size_t)row * GK + kt * 64 + schunk * 8, &dst[slot * 512]);
    }
  };

  f32x4 acc[4][3];
#pragma unroll
  for (int m = 0; m < 4; ++m)
#pragma unroll
    for (int n = 0; n < 3; ++n) acc[m][n] = 0.f;

  stageA(0);
  stageB(0);
  stageA(1);
  asm volatile("s_waitcnt vmcnt(4)" ::: "memory");
  memfence_bar();

  for (int t = 0; t < GNT; ++t) {
    if (t + 1 < GNT) stageB(t + 1);
    if (t + 2 < GNT) stageA(t + 2);

    const u16* Ab = As[t % 3];
    const u16* Bb = Bs[t & 1];
    bf16x8 af[4][2], bfr[3][2];
#pragma unroll
    for (int m = 0; m < 4; ++m)
#pragma unroll
      for (int kk = 0; kk < 2; ++kk) {
        int r = wr * 64 + m * 16 + lr;
        af[m][kk] = *reinterpret_cast<const bf16x8*>(
            &Ab[r * 64 + (((kk * 4 + g) ^ (r & 7)) << 3)]);
      }
#pragma unroll
    for (int n = 0; n < 3; ++n)
#pragma unroll
      for (int kk = 0; kk < 2; ++kk) {
        int r = wc * 48 + n * 16 + lr;
        bfr[n][kk] = *reinterpret_cast<const bf16x8*>(
            &Bb[r * 64 + (((kk * 4 + g) ^ (r & 7)) << 3)]);
      }

    __builtin_amdgcn_s_setprio(1);
#pragma unroll
    for (int m = 0; m < 4; ++m)
#pragma unroll
      for (int n = 0; n < 3; ++n) {
        acc[m][n] = __builtin_amdgcn_mfma_f32_16x16x32_bf16(bfr[n][0], af[m][0], acc[m][n], 0, 0, 0);
        acc[m][n] = __builtin_amdgcn_mfma_f32_16x16x32_bf16(bfr[n][1], af[m][1], acc[m][n], 0, 0, 0);
      }
    __builtin_amdgcn_s_setprio(0);

    if (t + 3 <= GNT) {
      asm volatile("s_waitcnt vmcnt(4)" ::: "memory");
      memfence_bar();
    } else if (t + 2 == GNT) {
      asm volatile("s_waitcnt vmcnt(0)" ::: "memory");
      memfence_bar();
    }
  }

  const int row0 = mx * 128 + wr * 64 + lr;
  const int col0 = ny * 96 + wc * 48 + g * 4;
#pragma unroll
  for (int m = 0; m < 4; ++m)
#pragma unroll
    for (int n = 0; n < 3; ++n) {
      int row = row0 + m * 16;
      int col = col0 + n * 16;
      float4 bv = *reinterpret_cast<const float4*>(&bias[col]);
      float v0 = acc[m][n][0] + bv.x, v1 = acc[m][n][1] + bv.y;
      float v2 = acc[m][n][2] + bv.z, v3 = acc[m][n][3] + bv.w;
      if (OUT_BF16) {
        ushort4 pw;
        pw.x = f2bf(v0); pw.y = f2bf(v1); pw.z = f2bf(v2); pw.w = f2bf(v3);
        *reinterpret_cast<ushort4*>(&((u16*)Cv)[(size_t)row * Ndim + col]) = pw;
      } else {
        *reinterpret_cast<float4*>(&((float*)Cv)[(size_t)row * Ndim + col]) =
            make_float4(v0, v1, v2, v3);
      }
    }
}

// Fused attention (round-12, unchanged): swapped QK^T, wave-private P,
// exp2 builtin + cvt_pk bf16 pack.
__global__ __launch_bounds__(256, 3) void attn_kernel(const u16* __restrict__ qkv,
                                                      const u16* __restrict__ vt,
                                                      u16* __restrict__ ctx) {
  const int bh = blockIdx.x;
  const int b = bh / HEADS, h = bh % HEADS;
  const int qt = blockIdx.y;
  const int tid = threadIdx.x, wave = tid >> 6, lane = tid & 63;
  const int lr = lane & 15, g = lane >> 4;

  __shared__ u16 Ks[2][64 * 64];
  __shared__ u16 Vs[2][64 * 64];
  __shared__ u16 Ps[128 * 64];

  const size_t tok0 = (size_t)b * SEQ;
  const int q0 = qt * 128;
  const int mbase = wave * 32;

  bf16x8 qf[2][2];
#pragma unroll
  for (int mi = 0; mi < 2; ++mi)
#pragma unroll
    for (int dk = 0; dk < 2; ++dk)
      qf[mi][dk] = *reinterpret_cast<const bf16x8*>(
          qkv + (tok0 + q0 + mbase + mi * 16 + lr) * TD + h * HDIM + dk * 32 + g * 8);

  const int srow = lane >> 3;
  const int schunk = (lane & 7) ^ srow;
  const u16* vbase = vt + (size_t)bh * (HDIM * SEQ);

  auto stage = [&](int kb, int buf) {
#pragma unroll
    for (int c2 = 0; c2 < 2; ++c2) {
      int call = wave * 2 + c2;
      int row  = call * 8 + srow;
      gload_lds16(qkv + (tok0 + kb * 64 + row) * TD + EMBED + h * HDIM + schunk * 8,
                  &Ks[buf][call * 512]);
      gload_lds16(vbase + (size_t)row * SEQ + kb * 64 + schunk * 8,
                  &Vs[buf][call * 512]);
    }
  };

  f32x4 oacc[2][4];
#pragma unroll
  for (int mi = 0; mi < 2; ++mi)
#pragma unroll
    for (int e = 0; e < 4; ++e) oacc[mi][e] = 0.f;
  float psum[2] = {0.f, 0.f};

  stage(0, 0);
  asm volatile("s_waitcnt vmcnt(0)" ::: "memory");
  memfence_bar();

  int cur = 0;
  for (int kb = 0; kb < 16; ++kb) {
    if (kb < 15) stage(kb + 1, cur ^ 1);

    bf16x8 ka[4][2], vb2[4][2];
#pragma unroll
    for (int n = 0; n < 4; ++n)
#pragma unroll
      for (int dk = 0; dk < 2; ++dk) {
        int r = n * 16 + lr;
        int c = dk * 4 + g;
        ka[n][dk]  = *reinterpret_cast<const bf16x8*>(&Ks[cur][r * 64 + ((c ^ (r & 7)) << 3)]);
        vb2[n][dk] = *reinterpret_cast<const bf16x8*>(&Vs[cur][r * 64 + ((c ^ (r & 7)) << 3)]);
      }

#pragma unroll
    for (int mi = 0; mi < 2; ++mi) {
      int m = mbase + mi * 16 + lr;
      int pswz = (lr & 7) << 1;
#pragma unroll
      for (int n = 0; n < 4; ++n) {
        f32x4 s = 0.f;
        __builtin_amdgcn_s_setprio(1);
        s = __builtin_amdgcn_mfma_f32_16x16x32_bf16(ka[n][0], qf[mi][0], s, 0, 0, 0);
        s = __builtin_amdgcn_mfma_f32_16x16x32_bf16(ka[n][1], qf[mi][1], s, 0, 0, 0);
        __builtin_amdgcn_s_setprio(0);
        float e0 = EXP2(s[0]), e1 = EXP2(s[1]);
        float e2 = EXP2(s[2]), e3 = EXP2(s[3]);
        psum[mi] += (e0 + e1) + (e2 + e3);
        uint2 pw;
        pw.x = cvt_pk_bf16(e0, e1);
        pw.y = cvt_pk_bf16(e2, e3);
        int gran = n * 4 + g;
        *reinterpret_cast<uint2*>(&Ps[m * 64 + ((gran ^ pswz) << 2)]) = pw;
      }
    }

#pragma unroll
    for (int mi = 0; mi < 2; ++mi) {
      bf16x8 pa[2];
#pragma unroll
      for (int kk = 0; kk < 2; ++kk) {
        int r = mbase + mi * 16 + lr;
        int c = kk * 4 + g;
        pa[kk] = *reinterpret_cast<const bf16x8*>(&Ps[r * 64 + ((c ^ (r & 7)) << 3)]);
      }
      __builtin_amdgcn_s_setprio(1);
#pragma unroll
      for (int e = 0; e < 4; ++e) {
        oacc[mi][e] = __builtin_amdgcn_mfma_f32_16x16x32_bf16(pa[0], vb2[e][0], oacc[mi][e], 0, 0, 0);
        oacc[mi][e] = __builtin_amdgcn_mfma_f32_16x16x32_bf16(pa[1], vb2[e][1], oacc[mi][e], 0, 0, 0);
      }
      __builtin_amdgcn_s_setprio(0);
    }

    if (kb < 15) {
      asm volatile("s_waitcnt vmcnt(0)" ::: "memory");
      memfence_bar();
    }
    cur ^= 1;
  }

  float scl[2][4];
#pragma unroll
  for (int mi = 0; mi < 2; ++mi) {
    float v = psum[mi];
    v += __shfl_xor(v, 16);
    v += __shfl_xor(v, 32);
    v = 0.125f / v;
#pragma unroll
    for (int j = 0; j < 4; ++j) scl[mi][j] = __shfl(v, 4 * g + j);
  }
#pragma unroll
  for (int mi = 0; mi < 2; ++mi)
#pragma unroll
    for (int e = 0; e < 4; ++e)
#pragma unroll
      for (int j = 0; j < 4; ++j) {
        float v = oacc[mi][e][j] * scl[mi][j];
        ctx[(tok0 + q0 + mbase + mi * 16 + 4 * g + j) * EMBED + h * HDIM + e * 16 + lr] = f2bf(v);
      }
}

extern "C" void kernel_launch(void* const* d_in, const int* in_sizes, int n_in,
                              void* d_out, int out_size, void* d_ws, size_t ws_size,
                              hipStream_t stream) {
  (void)in_sizes; (void)n_in; (void)out_size;
  const float* x     = (const float*)d_in[0];
  const float* Wqkv  = (const float*)d_in[1];
  const float* bqkv  = (const float*)d_in[2];
  const float* Wproj = (const float*)d_in[3];
  const float* bproj = (const float*)d_in[4];
  float* out = (float*)d_out;

  char* ws = (char*)d_ws;
  size_t off = 0;
  auto alloc = [&](size_t bytes) {
    char* p = ws + off;
    off += (bytes + 255) & ~(size_t)255;
    return p;
  };
  u16* xb     = (u16*)alloc((size_t)MTOK * EMBED * 2);
  u16* wqkvb  = (u16*)alloc((size_t)TD * EMBED * 2);
  u16* wprojb = (u16*)alloc((size_t)EMBED * EMBED * 2);
  u16* qkvb   = (u16*)alloc((size_t)MTOK * TD * 2);
  u16* ctxb   = (u16*)alloc((size_t)MTOK * EMBED * 2);
  u16* vtb    = (u16*)alloc((size_t)MTOK * EMBED * 2);  // V transposed [bh][e][tok]
  if (off > ws_size) return;  // workspace too small: loud failure

  cast3_kernel<<<dim3(2048), dim3(256), 0, stream>>>(x, Wqkv, Wproj, xb, wqkvb, wprojb);

  // QKV projection + fused V-transpose: grid 64x9 = 576 blocks, 2 ny-tiles each
  gemm_qkv<<<dim3(576), dim3(256), 0, stream>>>(xb, wqkvb, bqkv, qkvb, vtb);
  // fused attention (Q pre-scaled by log2e -> v_exp_f32 via builtin)
  attn_kernel<<<dim3(96, 8), dim3(256), 0, stream>>>(qkvb, vtb, ctxb);
  // output projection: grid 64x8 = 512 blocks = 1.0 round @ 2 blocks/CU
  gemm_min2<false><<<dim3(512), dim3(256), 0, stream>>>(ctxb, wprojb, bproj, out, 8, EMBED);
}

// Round 14
// 113.015 us; speedup vs baseline: 1.1407x; 1.1407x over previous
//
#include <hip/hip_runtime.h>

typedef unsigned short u16;
typedef __attribute__((ext_vector_type(8))) short bf16x8;   // 8 bf16 (4 VGPRs)
typedef __attribute__((ext_vector_type(4))) float f32x4;

#define HEADS 12
#define HDIM  64
#define EMBED 768
#define TD    2304
#define SEQ   1024
#define MTOK  8192
#define GK    768
#define GNT   12    // GK / 64
#define LOG2E 1.4426950408889634f

// HW 2^x: compiler-known TRANS intrinsic (hazard-safe), not inline asm.
#if __has_builtin(__builtin_amdgcn_exp2f)
#define EXP2(x) __builtin_amdgcn_exp2f(x)
#else
#define EXP2(x) exp2f(x)
#endif

// round-to-nearest-even f32 -> bf16
__device__ __forceinline__ u16 f2bf(float f) {
  union { float f; unsigned u; } x; x.f = f;
  unsigned r = x.u + 0x7fffu + ((x.u >> 16) & 1u);
  return (u16)(r >> 16);
}

// pack 2 f32 -> 2 bf16 in one inst (D[15:0]=lo, D[31:16]=hi) — T12 recipe
__device__ __forceinline__ unsigned cvt_pk_bf16(float lo, float hi) {
  unsigned r;
  asm("v_cvt_pk_bf16_f32 %0, %1, %2" : "=v"(r) : "v"(lo), "v"(hi));
  return r;
}

// all three f32->bf16 casts in one launch
__global__ void cast3_kernel(const float* __restrict__ x, const float* __restrict__ wq,
                             const float* __restrict__ wp, u16* __restrict__ xb,
                             u16* __restrict__ wqb, u16* __restrict__ wpb) {
  const int N1 = MTOK * EMBED / 4, N2 = TD * EMBED / 4, N3 = EMBED * EMBED / 4;
  int i = blockIdx.x * blockDim.x + threadIdx.x;
  int st = gridDim.x * blockDim.x;
  for (; i < N1 + N2 + N3; i += st) {
    const float* s; u16* d; int j;
    if (i < N1)           { s = x;  d = xb;  j = i; }
    else if (i < N1 + N2) { s = wq; d = wqb; j = i - N1; }
    else                  { s = wp; d = wpb; j = i - N1 - N2; }
    float4 v = reinterpret_cast<const float4*>(s)[j];
    ushort4 o;
    o.x = f2bf(v.x); o.y = f2bf(v.y); o.z = f2bf(v.z); o.w = f2bf(v.w);
    reinterpret_cast<ushort4*>(d)[j] = o;
  }
}

__device__ __forceinline__ void gload_lds16(const u16* g, u16* l) {
  __builtin_amdgcn_global_load_lds(
      (const __attribute__((address_space(1))) unsigned*)g,
      (__attribute__((address_space(3))) unsigned*)l, 16, 0, 0);
}

__device__ __forceinline__ void memfence_bar() {
  asm volatile("" ::: "memory");
  __builtin_amdgcn_s_barrier();
  asm volatile("" ::: "memory");
}

// ---------------- QKV GEMM: min-2-phase + 3-way ny-merge (round-12 best) ----
__global__ __launch_bounds__(256, 2) void gemm_qkv(const u16* __restrict__ A,
                                                   const u16* __restrict__ B,
                                                   const float* __restrict__ bias,
                                                   u16* __restrict__ Cq,
                                                   u16* __restrict__ vt) {
  __shared__ u16 As[3][128 * 64];   // ring-3, buf = u % 3
  __shared__ u16 Bs[2][96 * 64];    // dbuf,   buf = u & 1
  const int tid  = threadIdx.x;
  const int wave = tid >> 6, lane = tid & 63;
  const int wr = wave >> 1, wc = wave & 1;
  const int lr = lane & 15, g = lane >> 4;

  const int swz = (blockIdx.x & 7) * 64 + (blockIdx.x >> 3);
  const int ny = swz & 7, mx = swz >> 3;

  const u16* Ag = A + (size_t)(mx * 128) * GK;

  const int srow   = lane >> 3;             // row within 8-row slot
  const int schunk = (lane & 7) ^ srow;     // pre-swizzled source 16B-chunk

  auto stageA = [&](int u) {                // 4 gloads/thread; kt = u%12
    u16* dst = As[u % 3];
    const int k0 = (u % GNT) * 64;
#pragma unroll
    for (int c = 0; c < 4; ++c) {
      int slot = wave * 4 + c;
      int row  = slot * 8 + srow;
      gload_lds16(Ag + (size_t)row * GK + k0 + schunk * 8, &dst[slot * 512]);
    }
  };
  auto stageB = [&](int u) {                // 3 gloads/thread
    u16* dst = Bs[u & 1];
    const int k0 = (u % GNT) * 64;
    const u16* Bg = B + (size_t)((ny + (u / GNT) * 8) * 96) * GK;
#pragma unroll
    for (int c = 0; c < 3; ++c) {
      int slot = wave * 3 + c;
      int row  = slot * 8 + srow;
      gload_lds16(Bg + (size_t)row * GK + k0 + schunk * 8, &dst[slot * 512]);
    }
  };

  f32x4 acc[4][3];
#pragma unroll
  for (int m = 0; m < 4; ++m)
#pragma unroll
    for (int n = 0; n < 3; ++n) acc[m][n] = 0.f;

  const int TOT = 3 * GNT;   // 36
  stageA(0);
  stageB(0);
  stageA(1);
  asm volatile("s_waitcnt vmcnt(4)" ::: "memory");
  memfence_bar();

  for (int u = 0; u < TOT; ++u) {
    if (u + 1 < TOT) stageB(u + 1);
    if (u + 2 < TOT) stageA(u + 2);

    const u16* Ab = As[u % 3];
    const u16* Bb = Bs[u & 1];
    bf16x8 af[4][2], bfr[3][2];
#pragma unroll
    for (int m = 0; m < 4; ++m)
#pragma unroll
      for (int kk = 0; kk < 2; ++kk) {
        int r = wr * 64 + m * 16 + lr;
        af[m][kk] = *reinterpret_cast<const bf16x8*>(
            &Ab[r * 64 + (((kk * 4 + g) ^ (r & 7)) << 3)]);
      }
#pragma unroll
    for (int n = 0; n < 3; ++n)
#pragma unroll
      for (int kk = 0; kk < 2; ++kk) {
        int r = wc * 48 + n * 16 + lr;
        bfr[n][kk] = *reinterpret_cast<const bf16x8*>(
            &Bb[r * 64 + (((kk * 4 + g) ^ (r & 7)) << 3)]);
      }

    __builtin_amdgcn_s_setprio(1);
#pragma unroll
    for (int m = 0; m < 4; ++m)
#pragma unroll
      for (int n = 0; n < 3; ++n) {
        acc[m][n] = __builtin_amdgcn_mfma_f32_16x16x32_bf16(bfr[n][0], af[m][0], acc[m][n], 0, 0, 0);
        acc[m][n] = __builtin_amdgcn_mfma_f32_16x16x32_bf16(bfr[n][1], af[m][1], acc[m][n], 0, 0, 0);
      }
    __builtin_amdgcn_s_setprio(0);

    if (u + 3 <= TOT) {
      asm volatile("s_waitcnt vmcnt(4)" ::: "memory");
      memfence_bar();
    } else if (u + 2 == TOT) {
      asm volatile("s_waitcnt vmcnt(0)" ::: "memory");
      memfence_bar();
    }

    if ((u % GNT) == GNT - 1) {
      // ---- epilogue for segment seg = u/12 (stores don't touch LDS) ----
      const int seg = u / GNT;
      const int row0 = mx * 128 + wr * 64 + lr;
      const int colb = (ny + seg * 8) * 96 + wc * 48 + g * 4;
      if (seg < 2) {
        const float sc = (seg == 0) ? LOG2E : 1.f;   // Q pre-scaled for exp2
#pragma unroll
        for (int m = 0; m < 4; ++m)
#pragma unroll
          for (int n = 0; n < 3; ++n) {
            int row = row0 + m * 16;
            int col = colb + n * 16;
            float4 bv = *reinterpret_cast<const float4*>(&bias[col]);
            ushort4 pw;
            pw.x = f2bf((acc[m][n][0] + bv.x) * sc);
            pw.y = f2bf((acc[m][n][1] + bv.y) * sc);
            pw.z = f2bf((acc[m][n][2] + bv.z) * sc);
            pw.w = f2bf((acc[m][n][3] + bv.w) * sc);
            *reinterpret_cast<ushort4*>(&Cq[(size_t)row * TD + col]) = pw;
            acc[m][n] = 0.f;
          }
      } else {
        // V columns: write transposed into vt[bh][e][tok]
#pragma unroll
        for (int m = 0; m < 4; ++m) {
          int row = row0 + m * 16;                 // token
          int b   = row >> 10;
          int tk  = row & 1023;
#pragma unroll
          for (int n = 0; n < 3; ++n) {
            int col = colb + n * 16;
            float4 bv = *reinterpret_cast<const float4*>(&bias[col]);
#pragma unroll
            for (int j = 0; j < 4; ++j) {
              int vcol = col + j - 2 * EMBED;      // 0..767
              int h = vcol >> 6, e = vcol & 63;
              float v = acc[m][n][j] + (j == 0 ? bv.x : j == 1 ? bv.y : j == 2 ? bv.z : bv.w);
              vt[((size_t)(b * HEADS + h) * HDIM + e) * SEQ + tk] = f2bf(v);
            }
            acc[m][n] = 0.f;
          }
        }
      }
    }
  }
}

// ---------------- proj GEMM (min-2-phase, unchanged) ----------------
template <bool OUT_BF16>
__global__ __launch_bounds__(256, 2) void gemm_min2(const u16* __restrict__ A,
                                                    const u16* __restrict__ B,
                                                    const float* __restrict__ bias,
                                                    void* __restrict__ Cv,
                                                    int NBN, int Ndim) {
  __shared__ u16 As[3][128 * 64];
  __shared__ u16 Bs[2][96 * 64];
  const int tid  = threadIdx.x;
  const int wave = tid >> 6, lane = tid & 63;
  const int wr = wave >> 1, wc = wave & 1;
  const int lr = lane & 15, g = lane >> 4;

  const int nwg = gridDim.x;
  const int swz = (blockIdx.x & 7) * (nwg >> 3) + (blockIdx.x >> 3);
  const int ny = swz % NBN, mx = swz / NBN;

  const u16* Ag = A + (size_t)(mx * 128) * GK;
  const u16* Bg = B + (size_t)(ny * 96) * GK;

  const int srow   = lane >> 3;
  const int schunk = (lane & 7) ^ srow;

  auto stageA = [&](int kt) {
    u16* dst = As[kt % 3];
#pragma unroll
    for (int c = 0; c < 4; ++c) {
      int slot = wave * 4 + c;
      int row  = slot * 8 + srow;
      gload_lds16(Ag + (size_t)row * GK + kt * 64 + schunk * 8, &dst[slot * 512]);
    }
  };
  auto stageB = [&](int kt) {
    u16* dst = Bs[kt & 1];
#pragma unroll
    for (int c = 0; c < 3; ++c) {
      int slot = wave * 3 + c;
      int row  = slot * 8 + srow;
      gload_lds16(Bg + (size_t)row * GK + kt * 64 + schunk * 8, &dst[slot * 512]);
    }
  };

  f32x4 acc[4][3];
#pragma unroll
  for (int m = 0; m < 4; ++m)
#pragma unroll
    for (int n = 0; n < 3; ++n) acc[m][n] = 0.f;

  stageA(0);
  stageB(0);
  stageA(1);
  asm volatile("s_waitcnt vmcnt(4)" ::: "memory");
  memfence_bar();

  for (int t = 0; t < GNT; ++t) {
    if (t + 1 < GNT) stageB(t + 1);
    if (t + 2 < GNT) stageA(t + 2);

    const u16* Ab = As[t % 3];
    const u16* Bb = Bs[t & 1];
    bf16x8 af[4][2], bfr[3][2];
#pragma unroll
    for (int m = 0; m < 4; ++m)
#pragma unroll
      for (int kk = 0; kk < 2; ++kk) {
        int r = wr * 64 + m * 16 + lr;
        af[m][kk] = *reinterpret_cast<const bf16x8*>(
            &Ab[r * 64 + (((kk * 4 + g) ^ (r & 7)) << 3)]);
      }
#pragma unroll
    for (int n = 0; n < 3; ++n)
#pragma unroll
      for (int kk = 0; kk < 2; ++kk) {
        int r = wc * 48 + n * 16 + lr;
        bfr[n][kk] = *reinterpret_cast<const bf16x8*>(
            &Bb[r * 64 + (((kk * 4 + g) ^ (r & 7)) << 3)]);
      }

    __builtin_amdgcn_s_setprio(1);
#pragma unroll
    for (int m = 0; m < 4; ++m)
#pragma unroll
      for (int n = 0; n < 3; ++n) {
        acc[m][n] = __builtin_amdgcn_mfma_f32_16x16x32_bf16(bfr[n][0], af[m][0], acc[m][n], 0, 0, 0);
        acc[m][n] = __builtin_amdgcn_mfma_f32_16x16x32_bf16(bfr[n][1], af[m][1], acc[m][n], 0, 0, 0);
      }
    __builtin_amdgcn_s_setprio(0);

    if (t + 3 <= GNT) {
      asm volatile("s_waitcnt vmcnt(4)" ::: "memory");
      memfence_bar();
    } else if (t + 2 == GNT) {
      asm volatile("s_waitcnt vmcnt(0)" ::: "memory");
      memfence_bar();
    }
  }

  const int row0 = mx * 128 + wr * 64 + lr;
  const int col0 = ny * 96 + wc * 48 + g * 4;
#pragma unroll
  for (int m = 0; m < 4; ++m)
#pragma unroll
    for (int n = 0; n < 3; ++n) {
      int row = row0 + m * 16;
      int col = col0 + n * 16;
      float4 bv = *reinterpret_cast<const float4*>(&bias[col]);
      float v0 = acc[m][n][0] + bv.x, v1 = acc[m][n][1] + bv.y;
      float v2 = acc[m][n][2] + bv.z, v3 = acc[m][n][3] + bv.w;
      if (OUT_BF16) {
        ushort4 pw;
        pw.x = f2bf(v0); pw.y = f2bf(v1); pw.z = f2bf(v2); pw.w = f2bf(v3);
        *reinterpret_cast<ushort4*>(&((u16*)Cv)[(size_t)row * Ndim + col]) = pw;
      } else {
        *reinterpret_cast<float4*>(&((float*)Cv)[(size_t)row * Ndim + col]) =
            make_float4(v0, v1, v2, v3);
      }
    }
}

// Fused attention (round-12 best): swapped QK^T, wave-private P,
// exp2 builtin + cvt_pk bf16 pack.
__global__ __launch_bounds__(256, 3) void attn_kernel(const u16* __restrict__ qkv,
                                                      const u16* __restrict__ vt,
                                                      u16* __restrict__ ctx) {
  const int bh = blockIdx.x;
  const int b = bh / HEADS, h = bh % HEADS;
  const int qt = blockIdx.y;
  const int tid = threadIdx.x, wave = tid >> 6, lane = tid & 63;
  const int lr = lane & 15, g = lane >> 4;

  __shared__ u16 Ks[2][64 * 64];
  __shared__ u16 Vs[2][64 * 64];
  __shared__ u16 Ps[128 * 64];

  const size_t tok0 = (size_t)b * SEQ;
  const int q0 = qt * 128;
  const int mbase = wave * 32;

  bf16x8 qf[2][2];
#pragma unroll
  for (int mi = 0; mi < 2; ++mi)
#pragma unroll
    for (int dk = 0; dk < 2; ++dk)
      qf[mi][dk] = *reinterpret_cast<const bf16x8*>(
          qkv + (tok0 + q0 + mbase + mi * 16 + lr) * TD + h * HDIM + dk * 32 + g * 8);

  const int srow = lane >> 3;
  const int schunk = (lane & 7) ^ srow;
  const u16* vbase = vt + (size_t)bh * (HDIM * SEQ);

  auto stage = [&](int kb, int buf) {
#pragma unroll
    for (int c2 = 0; c2 < 2; ++c2) {
      int call = wave * 2 + c2;
      int row  = call * 8 + srow;
      gload_lds16(qkv + (tok0 + kb * 64 + row) * TD + EMBED + h * HDIM + schunk * 8,
                  &Ks[buf][call * 512]);
      gload_lds16(vbase + (size_t)row * SEQ + kb * 64 + schunk * 8,
                  &Vs[buf][call * 512]);
    }
  };

  f32x4 oacc[2][4];
#pragma unroll
  for (int mi = 0; mi < 2; ++mi)
#pragma unroll
    for (int e = 0; e < 4; ++e) oacc[mi][e] = 0.f;
  float psum[2] = {0.f, 0.f};

  stage(0, 0);
  asm volatile("s_waitcnt vmcnt(0)" ::: "memory");
  memfence_bar();

  int cur = 0;
  for (int kb = 0; kb < 16; ++kb) {
    if (kb < 15) stage(kb + 1, cur ^ 1);

    bf16x8 ka[4][2], vb2[4][2];
#pragma unroll
    for (int n = 0; n < 4; ++n)
#pragma unroll
      for (int dk = 0; dk < 2; ++dk) {
        int r = n * 16 + lr;
        int c = dk * 4 + g;
        ka[n][dk]  = *reinterpret_cast<const bf16x8*>(&Ks[cur][r * 64 + ((c ^ (r & 7)) << 3)]);
        vb2[n][dk] = *reinterpret_cast<const bf16x8*>(&Vs[cur][r * 64 + ((c ^ (r & 7)) << 3)]);
      }

#pragma unroll
    for (int mi = 0; mi < 2; ++mi) {
      int m = mbase + mi * 16 + lr;
      int pswz = (lr & 7) << 1;
#pragma unroll
      for (int n = 0; n < 4; ++n) {
        f32x4 s = 0.f;
        __builtin_amdgcn_s_setprio(1);
        s = __builtin_amdgcn_mfma_f32_16x16x32_bf16(ka[n][0], qf[mi][0], s, 0, 0, 0);
        s = __builtin_amdgcn_mfma_f32_16x16x32_bf16(ka[n][1], qf[mi][1], s, 0, 0, 0);
        __builtin_amdgcn_s_setprio(0);
        float e0 = EXP2(s[0]), e1 = EXP2(s[1]);
        float e2 = EXP2(s[2]), e3 = EXP2(s[3]);
        psum[mi] += (e0 + e1) + (e2 + e3);
        uint2 pw;
        pw.x = cvt_pk_bf16(e0, e1);
        pw.y = cvt_pk_bf16(e2, e3);
        int gran = n * 4 + g;
        *reinterpret_cast<uint2*>(&Ps[m * 64 + ((gran ^ pswz) << 2)]) = pw;
      }
    }

#pragma unroll
    for (int mi = 0; mi < 2; ++mi) {
      bf16x8 pa[2];
#pragma unroll
      for (int kk = 0; kk < 2; ++kk) {
        int r = mbase + mi * 16 + lr;
        int c = kk * 4 + g;
        pa[kk] = *reinterpret_cast<const bf16x8*>(&Ps[r * 64 + ((c ^ (r & 7)) << 3)]);
      }
      __builtin_amdgcn_s_setprio(1);
#pragma unroll
      for (int e = 0; e < 4; ++e) {
        oacc[mi][e] = __builtin_amdgcn_mfma_f32_16x16x32_bf16(pa[0], vb2[e][0], oacc[mi][e], 0, 0, 0);
        oacc[mi][e] = __builtin_amdgcn_mfma_f32_16x16x32_bf16(pa[1], vb2[e][1], oacc[mi][e], 0, 0, 0);
      }
      __builtin_amdgcn_s_setprio(0);
    }

    if (kb < 15) {
      asm volatile("s_waitcnt vmcnt(0)" ::: "memory");
      memfence_bar();
    }
    cur ^= 1;
  }

  float scl[2][4];
#pragma unroll
  for (int mi = 0; mi < 2; ++mi) {
    float v = psum[mi];
    v += __shfl_xor(v, 16);
    v += __shfl_xor(v, 32);
    v = 0.125f / v;
#pragma unroll
    for (int j = 0; j < 4; ++j) scl[mi][j] = __shfl(v, 4 * g + j);
  }
#pragma unroll
  for (int mi = 0; mi < 2; ++mi)
#pragma unroll
    for (int e = 0; e < 4; ++e)
#pragma unroll
      for (int j = 0; j < 4; ++j) {
        float v = oacc[mi][e][j] * scl[mi][j];
        ctx[(tok0 + q0 + mbase + mi * 16 + 4 * g + j) * EMBED + h * HDIM + e * 16 + lr] = f2bf(v);
      }
}

extern "C" void kernel_launch(void* const* d_in, const int* in_sizes, int n_in,
                              void* d_out, int out_size, void* d_ws, size_t ws_size,
                              hipStream_t stream) {
  (void)in_sizes; (void)n_in; (void)out_size;
  const float* x     = (const float*)d_in[0];
  const float* Wqkv  = (const float*)d_in[1];
  const float* bqkv  = (const float*)d_in[2];
  const float* Wproj = (const float*)d_in[3];
  const float* bproj = (const float*)d_in[4];
  float* out = (float*)d_out;

  char* ws = (char*)d_ws;
  size_t off = 0;
  auto alloc = [&](size_t bytes) {
    char* p = ws + off;
    off += (bytes + 255) & ~(size_t)255;
    return p;
  };
  u16* xb     = (u16*)alloc((size_t)MTOK * EMBED * 2);
  u16* wqkvb  = (u16*)alloc((size_t)TD * EMBED * 2);
  u16* wprojb = (u16*)alloc((size_t)EMBED * EMBED * 2);
  u16* qkvb   = (u16*)alloc((size_t)MTOK * TD * 2);
  u16* ctxb   = (u16*)alloc((size_t)MTOK * EMBED * 2);
  u16* vtb    = (u16*)alloc((size_t)MTOK * EMBED * 2);  // V transposed [bh][e][tok]
  if (off > ws_size) return;  // workspace too small: loud failure

  cast3_kernel<<<dim3(2048), dim3(256), 0, stream>>>(x, Wqkv, Wproj, xb, wqkvb, wprojb);

  // QKV projection + fused V-transpose: grid 64x8 = 512 blocks, 3 ny-segments each
  gemm_qkv<<<dim3(512), dim3(256), 0, stream>>>(xb, wqkvb, bqkv, qkvb, vtb);
  // fused attention (Q pre-scaled by log2e -> v_exp_f32 via builtin)
  attn_kernel<<<dim3(96, 8), dim3(256), 0, stream>>>(qkvb, vtb, ctxb);
  // output projection: grid 64x8 = 512 blocks = 1.0 round @ 2 blocks/CU
  gemm_min2<false><<<dim3(512), dim3(256), 0, stream>>>(ctxb, wprojb, bproj, out, 8, EMBED);
}

// Round 15
// 112.826 us; speedup vs baseline: 1.1426x; 1.0017x over previous
//
#include <hip/hip_runtime.h>

typedef unsigned short u16;
typedef __attribute__((ext_vector_type(8))) short bf16x8;   // 8 bf16 (4 VGPRs)
typedef __attribute__((ext_vector_type(4))) float f32x4;

#define HEADS 12
#define HDIM  64
#define EMBED 768
#define TD    2304
#define SEQ   1024
#define MTOK  8192
#define GK    768
#define GNT   12    // GK / 64
#define LOG2E 1.4426950408889634f

// HW 2^x: compiler-known TRANS intrinsic (hazard-safe), not inline asm.
#if __has_builtin(__builtin_amdgcn_exp2f)
#define EXP2(x) __builtin_amdgcn_exp2f(x)
#else
#define EXP2(x) exp2f(x)
#endif

// round-to-nearest-even f32 -> bf16
__device__ __forceinline__ u16 f2bf(float f) {
  union { float f; unsigned u; } x; x.f = f;
  unsigned r = x.u + 0x7fffu + ((x.u >> 16) & 1u);
  return (u16)(r >> 16);
}

// pack 2 f32 -> 2 bf16 in one inst (D[15:0]=lo, D[31:16]=hi) — T12 recipe
__device__ __forceinline__ unsigned cvt_pk_bf16(float lo, float hi) {
  unsigned r;
  asm("v_cvt_pk_bf16_f32 %0, %1, %2" : "=v"(r) : "v"(lo), "v"(hi));
  return r;
}

// all three f32->bf16 casts in one launch
__global__ void cast3_kernel(const float* __restrict__ x, const float* __restrict__ wq,
                             const float* __restrict__ wp, u16* __restrict__ xb,
                             u16* __restrict__ wqb, u16* __restrict__ wpb) {
  const int N1 = MTOK * EMBED / 4, N2 = TD * EMBED / 4, N3 = EMBED * EMBED / 4;
  int i = blockIdx.x * blockDim.x + threadIdx.x;
  int st = gridDim.x * blockDim.x;
  for (; i < N1 + N2 + N3; i += st) {
    const float* s; u16* d; int j;
    if (i < N1)           { s = x;  d = xb;  j = i; }
    else if (i < N1 + N2) { s = wq; d = wqb; j = i - N1; }
    else                  { s = wp; d = wpb; j = i - N1 - N2; }
    float4 v = reinterpret_cast<const float4*>(s)[j];
    ushort4 o;
    o.x = f2bf(v.x); o.y = f2bf(v.y); o.z = f2bf(v.z); o.w = f2bf(v.w);
    reinterpret_cast<ushort4*>(d)[j] = o;
  }
}

__device__ __forceinline__ void gload_lds16(const u16* g, u16* l) {
  __builtin_amdgcn_global_load_lds(
      (const __attribute__((address_space(1))) unsigned*)g,
      (__attribute__((address_space(3))) unsigned*)l, 16, 0, 0);
}

__device__ __forceinline__ void memfence_bar() {
  asm volatile("" ::: "memory");
  __builtin_amdgcn_s_barrier();
  asm volatile("" ::: "memory");
}

// ---------------- QKV GEMM: min-2-phase + 3-way ny-merge (round-12 best) ----
__global__ __launch_bounds__(256, 2) void gemm_qkv(const u16* __restrict__ A,
                                                   const u16* __restrict__ B,
                                                   const float* __restrict__ bias,
                                                   u16* __restrict__ Cq,
                                                   u16* __restrict__ vt) {
  __shared__ u16 As[3][128 * 64];   // ring-3, buf = u % 3
  __shared__ u16 Bs[2][96 * 64];    // dbuf,   buf = u & 1
  const int tid  = threadIdx.x;
  const int wave = tid >> 6, lane = tid & 63;
  const int wr = wave >> 1, wc = wave & 1;
  const int lr = lane & 15, g = lane >> 4;

  const int swz = (blockIdx.x & 7) * 64 + (blockIdx.x >> 3);
  const int ny = swz & 7, mx = swz >> 3;

  const u16* Ag = A + (size_t)(mx * 128) * GK;

  const int srow   = lane >> 3;             // row within 8-row slot
  const int schunk = (lane & 7) ^ srow;     // pre-swizzled source 16B-chunk

  auto stageA = [&](int u) {                // 4 gloads/thread; kt = u%12
    u16* dst = As[u % 3];
    const int k0 = (u % GNT) * 64;
#pragma unroll
    for (int c = 0; c < 4; ++c) {
      int slot = wave * 4 + c;
      int row  = slot * 8 + srow;
      gload_lds16(Ag + (size_t)row * GK + k0 + schunk * 8, &dst[slot * 512]);
    }
  };
  auto stageB = [&](int u) {                // 3 gloads/thread
    u16* dst = Bs[u & 1];
    const int k0 = (u % GNT) * 64;
    const u16* Bg = B + (size_t)((ny + (u / GNT) * 8) * 96) * GK;
#pragma unroll
    for (int c = 0; c < 3; ++c) {
      int slot = wave * 3 + c;
      int row  = slot * 8 + srow;
      gload_lds16(Bg + (size_t)row * GK + k0 + schunk * 8, &dst[slot * 512]);
    }
  };

  f32x4 acc[4][3];
#pragma unroll
  for (int m = 0; m < 4; ++m)
#pragma unroll
    for (int n = 0; n < 3; ++n) acc[m][n] = 0.f;

  const int TOT = 3 * GNT;   // 36
  stageA(0);
  stageB(0);
  stageA(1);
  asm volatile("s_waitcnt vmcnt(4)" ::: "memory");
  memfence_bar();

  for (int u = 0; u < TOT; ++u) {
    if (u + 1 < TOT) stageB(u + 1);
    if (u + 2 < TOT) stageA(u + 2);

    const u16* Ab = As[u % 3];
    const u16* Bb = Bs[u & 1];
    bf16x8 af[4][2], bfr[3][2];
#pragma unroll
    for (int m = 0; m < 4; ++m)
#pragma unroll
      for (int kk = 0; kk < 2; ++kk) {
        int r = wr * 64 + m * 16 + lr;
        af[m][kk] = *reinterpret_cast<const bf16x8*>(
            &Ab[r * 64 + (((kk * 4 + g) ^ (r & 7)) << 3)]);
      }
#pragma unroll
    for (int n = 0; n < 3; ++n)
#pragma unroll
      for (int kk = 0; kk < 2; ++kk) {
        int r = wc * 48 + n * 16 + lr;
        bfr[n][kk] = *reinterpret_cast<const bf16x8*>(
            &Bb[r * 64 + (((kk * 4 + g) ^ (r & 7)) << 3)]);
      }

    __builtin_amdgcn_s_setprio(1);
#pragma unroll
    for (int m = 0; m < 4; ++m)
#pragma unroll
      for (int n = 0; n < 3; ++n) {
        acc[m][n] = __builtin_amdgcn_mfma_f32_16x16x32_bf16(bfr[n][0], af[m][0], acc[m][n], 0, 0, 0);
        acc[m][n] = __builtin_amdgcn_mfma_f32_16x16x32_bf16(bfr[n][1], af[m][1], acc[m][n], 0, 0, 0);
      }
    __builtin_amdgcn_s_setprio(0);

    if (u + 3 <= TOT) {
      asm volatile("s_waitcnt vmcnt(4)" ::: "memory");
      memfence_bar();
    } else if (u + 2 == TOT) {
      asm volatile("s_waitcnt vmcnt(0)" ::: "memory");
      memfence_bar();
    }

    if ((u % GNT) == GNT - 1) {
      // ---- epilogue for segment seg = u/12 (stores don't touch LDS) ----
      const int seg = u / GNT;
      const int row0 = mx * 128 + wr * 64 + lr;
      const int colb = (ny + seg * 8) * 96 + wc * 48 + g * 4;
      if (seg < 2) {
        const float sc = (seg == 0) ? LOG2E : 1.f;   // Q pre-scaled for exp2
#pragma unroll
        for (int m = 0; m < 4; ++m)
#pragma unroll
          for (int n = 0; n < 3; ++n) {
            int row = row0 + m * 16;
            int col = colb + n * 16;
            float4 bv = *reinterpret_cast<const float4*>(&bias[col]);
            ushort4 pw;
            pw.x = f2bf((acc[m][n][0] + bv.x) * sc);
            pw.y = f2bf((acc[m][n][1] + bv.y) * sc);
            pw.z = f2bf((acc[m][n][2] + bv.z) * sc);
            pw.w = f2bf((acc[m][n][3] + bv.w) * sc);
            *reinterpret_cast<ushort4*>(&Cq[(size_t)row * TD + col]) = pw;
            acc[m][n] = 0.f;
          }
      } else {
        // V columns: write transposed into vt[bh][e][tok]
#pragma unroll
        for (int m = 0; m < 4; ++m) {
          int row = row0 + m * 16;                 // token
          int b   = row >> 10;
          int tk  = row & 1023;
#pragma unroll
          for (int n = 0; n < 3; ++n) {
            int col = colb + n * 16;
            float4 bv = *reinterpret_cast<const float4*>(&bias[col]);
#pragma unroll
            for (int j = 0; j < 4; ++j) {
              int vcol = col + j - 2 * EMBED;      // 0..767
              int h = vcol >> 6, e = vcol & 63;
              float v = acc[m][n][j] + (j == 0 ? bv.x : j == 1 ? bv.y : j == 2 ? bv.z : bv.w);
              vt[((size_t)(b * HEADS + h) * HDIM + e) * SEQ + tk] = f2bf(v);
            }
            acc[m][n] = 0.f;
          }
        }
      }
    }
  }
}

// ---------------- proj GEMM (min-2-phase, unchanged) ----------------
template <bool OUT_BF16>
__global__ __launch_bounds__(256, 2) void gemm_min2(const u16* __restrict__ A,
                                                    const u16* __restrict__ B,
                                                    const float* __restrict__ bias,
                                                    void* __restrict__ Cv,
                                                    int NBN, int Ndim) {
  __shared__ u16 As[3][128 * 64];
  __shared__ u16 Bs[2][96 * 64];
  const int tid  = threadIdx.x;
  const int wave = tid >> 6, lane = tid & 63;
  const int wr = wave >> 1, wc = wave & 1;
  const int lr = lane & 15, g = lane >> 4;

  const int nwg = gridDim.x;
  const int swz = (blockIdx.x & 7) * (nwg >> 3) + (blockIdx.x >> 3);
  const int ny = swz % NBN, mx = swz / NBN;

  const u16* Ag = A + (size_t)(mx * 128) * GK;
  const u16* Bg = B + (size_t)(ny * 96) * GK;

  const int srow   = lane >> 3;
  const int schunk = (lane & 7) ^ srow;

  auto stageA = [&](int kt) {
    u16* dst = As[kt % 3];
#pragma unroll
    for (int c = 0; c < 4; ++c) {
      int slot = wave * 4 + c;
      int row  = slot * 8 + srow;
      gload_lds16(Ag + (size_t)row * GK + kt * 64 + schunk * 8, &dst[slot * 512]);
    }
  };
  auto stageB = [&](int kt) {
    u16* dst = Bs[kt & 1];
#pragma unroll
    for (int c = 0; c < 3; ++c) {
      int slot = wave * 3 + c;
      int row  = slot * 8 + srow;
      gload_lds16(Bg + (size_t)row * GK + kt * 64 + schunk * 8, &dst[slot * 512]);
    }
  };

  f32x4 acc[4][3];
#pragma unroll
  for (int m = 0; m < 4; ++m)
#pragma unroll
    for (int n = 0; n < 3; ++n) acc[m][n] = 0.f;

  stageA(0);
  stageB(0);
  stageA(1);
  asm volatile("s_waitcnt vmcnt(4)" ::: "memory");
  memfence_bar();

  for (int t = 0; t < GNT; ++t) {
    if (t + 1 < GNT) stageB(t + 1);
    if (t + 2 < GNT) stageA(t + 2);

    const u16* Ab = As[t % 3];
    const u16* Bb = Bs[t & 1];
    bf16x8 af[4][2], bfr[3][2];
#pragma unroll
    for (int m = 0; m < 4; ++m)
#pragma unroll
      for (int kk = 0; kk < 2; ++kk) {
        int r = wr * 64 + m * 16 + lr;
        af[m][kk] = *reinterpret_cast<const bf16x8*>(
            &Ab[r * 64 + (((kk * 4 + g) ^ (r & 7)) << 3)]);
      }
#pragma unroll
    for (int n = 0; n < 3; ++n)
#pragma unroll
      for (int kk = 0; kk < 2; ++kk) {
        int r = wc * 48 + n * 16 + lr;
        bfr[n][kk] = *reinterpret_cast<const bf16x8*>(
            &Bb[r * 64 + (((kk * 4 + g) ^ (r & 7)) << 3)]);
      }

    __builtin_amdgcn_s_setprio(1);
#pragma unroll
    for (int m = 0; m < 4; ++m)
#pragma unroll
      for (int n = 0; n < 3; ++n) {
        acc[m][n] = __builtin_amdgcn_mfma_f32_16x16x32_bf16(bfr[n][0], af[m][0], acc[m][n], 0, 0, 0);
        acc[m][n] = __builtin_amdgcn_mfma_f32_16x16x32_bf16(bfr[n][1], af[m][1], acc[m][n], 0, 0, 0);
      }
    __builtin_amdgcn_s_setprio(0);

    if (t + 3 <= GNT) {
      asm volatile("s_waitcnt vmcnt(4)" ::: "memory");
      memfence_bar();
    } else if (t + 2 == GNT) {
      asm volatile("s_waitcnt vmcnt(0)" ::: "memory");
      memfence_bar();
    }
  }

  const int row0 = mx * 128 + wr * 64 + lr;
  const int col0 = ny * 96 + wc * 48 + g * 4;
#pragma unroll
  for (int m = 0; m < 4; ++m)
#pragma unroll
    for (int n = 0; n < 3; ++n) {
      int row = row0 + m * 16;
      int col = col0 + n * 16;
      float4 bv = *reinterpret_cast<const float4*>(&bias[col]);
      float v0 = acc[m][n][0] + bv.x, v1 = acc[m][n][1] + bv.y;
      float v2 = acc[m][n][2] + bv.z, v3 = acc[m][n][3] + bv.w;
      if (OUT_BF16) {
        ushort4 pw;
        pw.x = f2bf(v0); pw.y = f2bf(v1); pw.z = f2bf(v2); pw.w = f2bf(v3);
        *reinterpret_cast<ushort4*>(&((u16*)Cv)[(size_t)row * Ndim + col]) = pw;
      } else {
        *reinterpret_cast<float4*>(&((float*)Cv)[(size_t)row * Ndim + col]) =
            make_float4(v0, v1, v2, v3);
      }
    }
}

// Fused attention: K ring-3 (2-tile prefetch, counted vmcnt(2)) + V dbuf;
// Ps halved to 8KB with mi-fused PV (QK->exp->Pwrite->Pread->PV per mi half).
// LDS 48KB -> 3 blocks/CU unchanged. Swapped QK^T; wave-private P.
__global__ __launch_bounds__(256, 3) void attn_kernel(const u16* __restrict__ qkv,
                                                      const u16* __restrict__ vt,
                                                      u16* __restrict__ ctx) {
  const int bh = blockIdx.x;
  const int b = bh / HEADS, h = bh % HEADS;
  const int qt = blockIdx.y;
  const int tid = threadIdx.x, wave = tid >> 6, lane = tid & 63;
  const int lr = lane & 15, g = lane >> 4;

  __shared__ u16 Ks[3][64 * 64];  // ring-3, buf = kb % 3
  __shared__ u16 Vs[2][64 * 64];  // dbuf,   buf = kb & 1
  __shared__ u16 Ps[64 * 64];     // wave-private 16 rows/wave, reused per mi

  const size_t tok0 = (size_t)b * SEQ;
  const int q0 = qt * 128;
  const int mbase = wave * 32;

  bf16x8 qf[2][2];
#pragma unroll
  for (int mi = 0; mi < 2; ++mi)
#pragma unroll
    for (int dk = 0; dk < 2; ++dk)
      qf[mi][dk] = *reinterpret_cast<const bf16x8*>(
          qkv + (tok0 + q0 + mbase + mi * 16 + lr) * TD + h * HDIM + dk * 32 + g * 8);

  const int srow = lane >> 3;
  const int schunk = (lane & 7) ^ srow;
  const u16* vbase = vt + (size_t)bh * (HDIM * SEQ);

  auto stageK = [&](int kb) {               // 2 gloads/thread
    u16* dst = Ks[kb % 3];
#pragma unroll
    for (int c2 = 0; c2 < 2; ++c2) {
      int call = wave * 2 + c2;
      int row  = call * 8 + srow;
      gload_lds16(qkv + (tok0 + kb * 64 + row) * TD + EMBED + h * HDIM + schunk * 8,
                  &dst[call * 512]);
    }
  };
  auto stageV = [&](int kb) {               // 2 gloads/thread
    u16* dst = Vs[kb & 1];
#pragma unroll
    for (int c2 = 0; c2 < 2; ++c2) {
      int call = wave * 2 + c2;
      int row  = call * 8 + srow;
      gload_lds16(vbase + (size_t)row * SEQ + kb * 64 + schunk * 8,
                  &dst[call * 512]);
    }
  };

  f32x4 oacc[2][4];
#pragma unroll
  for (int mi = 0; mi < 2; ++mi)
#pragma unroll
    for (int e = 0; e < 4; ++e) oacc[mi][e] = 0.f;
  float psum[2] = {0.f, 0.f};

  // prologue: K(0), V(0), K(1); wait K(0)+V(0), leave K(1) in flight
  stageK(0);
  stageV(0);
  stageK(1);
  asm volatile("s_waitcnt vmcnt(2)" ::: "memory");
  memfence_bar();

  for (int kb = 0; kb < 16; ++kb) {
    if (kb + 1 < 16) stageV(kb + 1);
    if (kb + 2 < 16) stageK(kb + 2);

    const u16* Kb = Ks[kb % 3];
    const u16* Vb = Vs[kb & 1];
    bf16x8 ka[4][2], vb2[4][2];
#pragma unroll
    for (int n = 0; n < 4; ++n)
#pragma unroll
      for (int dk = 0; dk < 2; ++dk) {
        int r = n * 16 + lr;
        int c = dk * 4 + g;
        ka[n][dk]  = *reinterpret_cast<const bf16x8*>(&Kb[r * 64 + ((c ^ (r & 7)) << 3)]);
        vb2[n][dk] = *reinterpret_cast<const bf16x8*>(&Vb[r * 64 + ((c ^ (r & 7)) << 3)]);
      }

    const int m = wave * 16 + lr;           // Ps row (16 rows/wave, reused per mi)
    const int pswz = (lr & 7) << 1;
#pragma unroll
    for (int mi = 0; mi < 2; ++mi) {
      // QK^T (swapped) -> exp2 -> P write (wave-private, no barrier)
#pragma unroll
      for (int n = 0; n < 4; ++n) {
        f32x4 s = 0.f;
        __builtin_amdgcn_s_setprio(1);
        s = __builtin_amdgcn_mfma_f32_16x16x32_bf16(ka[n][0], qf[mi][0], s, 0, 0, 0);
        s = __builtin_amdgcn_mfma_f32_16x16x32_bf16(ka[n][1], qf[mi][1], s, 0, 0, 0);
        __builtin_amdgcn_s_setprio(0);
        float e0 = EXP2(s[0]), e1 = EXP2(s[1]);
        float e2 = EXP2(s[2]), e3 = EXP2(s[3]);
        psum[mi] += (e0 + e1) + (e2 + e3);
        uint2 pw;
        pw.x = cvt_pk_bf16(e0, e1);
        pw.y = cvt_pk_bf16(e2, e3);
        int gran = n * 4 + g;
        *reinterpret_cast<uint2*>(&Ps[m * 64 + ((gran ^ pswz) << 2)]) = pw;
      }
      // PV for this mi half
      bf16x8 pa[2];
#pragma unroll
      for (int kk = 0; kk < 2; ++kk) {
        int c = kk * 4 + g;
        pa[kk] = *reinterpret_cast<const bf16x8*>(&Ps[m * 64 + ((c ^ (m & 7)) << 3)]);
      }
      __builtin_amdgcn_s_setprio(1);
#pragma unroll
      for (int e = 0; e < 4; ++e) {
        oacc[mi][e] = __builtin_amdgcn_mfma_f32_16x16x32_bf16(pa[0], vb2[e][0], oacc[mi][e], 0, 0, 0);
        oacc[mi][e] = __builtin_amdgcn_mfma_f32_16x16x32_bf16(pa[1], vb2[e][1], oacc[mi][e], 0, 0, 0);
      }
      __builtin_amdgcn_s_setprio(0);
    }

    if (kb <= 13) {
      asm volatile("s_waitcnt vmcnt(2)" ::: "memory");  // K(kb+1)+V(kb+1) landed
      memfence_bar();
    } else if (kb == 14) {
      asm volatile("s_waitcnt vmcnt(0)" ::: "memory");  // final tile drain
      memfence_bar();
    }
  }

  float scl[2][4];
#pragma unroll
  for (int mi = 0; mi < 2; ++mi) {
    float v = psum[mi];
    v += __shfl_xor(v, 16);
    v += __shfl_xor(v, 32);
    v = 0.125f / v;
#pragma unroll
    for (int j = 0; j < 4; ++j) scl[mi][j] = __shfl(v, 4 * g + j);
  }
#pragma unroll
  for (int mi = 0; mi < 2; ++mi)
#pragma unroll
    for (int e = 0; e < 4; ++e)
#pragma unroll
      for (int j = 0; j < 4; ++j) {
        float v = oacc[mi][e][j] * scl[mi][j];
        ctx[(tok0 + q0 + mbase + mi * 16 + 4 * g + j) * EMBED + h * HDIM + e * 16 + lr] = f2bf(v);
      }
}

extern "C" void kernel_launch(void* const* d_in, const int* in_sizes, int n_in,
                              void* d_out, int out_size, void* d_ws, size_t ws_size,
                              hipStream_t stream) {
  (void)in_sizes; (void)n_in; (void)out_size;
  const float* x     = (const float*)d_in[0];
  const float* Wqkv  = (const float*)d_in[1];
  const float* bqkv  = (const float*)d_in[2];
  const float* Wproj = (const float*)d_in[3];
  const float* bproj = (const float*)d_in[4];
  float* out = (float*)d_out;

  char* ws = (char*)d_ws;
  size_t off = 0;
  auto alloc = [&](size_t bytes) {
    char* p = ws + off;
    off += (bytes + 255) & ~(size_t)255;
    return p;
  };
  u16* xb     = (u16*)alloc((size_t)MTOK * EMBED * 2);
  u16* wqkvb  = (u16*)alloc((size_t)TD * EMBED * 2);
  u16* wprojb = (u16*)alloc((size_t)EMBED * EMBED * 2);
  u16* qkvb   = (u16*)alloc((size_t)MTOK * TD * 2);
  u16* ctxb   = (u16*)alloc((size_t)MTOK * EMBED * 2);
  u16* vtb    = (u16*)alloc((size_t)MTOK * EMBED * 2);  // V transposed [bh][e][tok]
  if (off > ws_size) return;  // workspace too small: loud failure

  cast3_kernel<<<dim3(2048), dim3(256), 0, stream>>>(x, Wqkv, Wproj, xb, wqkvb, wprojb);

  // QKV projection + fused V-transpose: grid 64x8 = 512 blocks, 3 ny-segments each
  gemm_qkv<<<dim3(512), dim3(256), 0, stream>>>(xb, wqkvb, bqkv, qkvb, vtb);
  // fused attention (Q pre-scaled by log2e -> v_exp_f32 via builtin)
  attn_kernel<<<dim3(96, 8), dim3(256), 0, stream>>>(qkvb, vtb, ctxb);
  // output projection: grid 64x8 = 512 blocks = 1.0 round @ 2 blocks/CU
  gemm_min2<false><<<dim3(512), dim3(256), 0, stream>>>(ctxb, wprojb, bproj, out, 8, EMBED);
}